// Round 2
// baseline (910.087 us; speedup 1.0000x reference)
//
#include <hip/hip_runtime.h>
#include <stdint.h>

// ---------------------------------------------------------------------------
// Subgraph GNN: out = sum_k MLP_k(hops_k), hops = [X, hop1@X, hop2@X, hop3@X]
// N=8192, IN_DIM=64, H1=128, H2=64, 4 branches.
//
// R4 changes vs R3 (hop_gemm was in-flight-bound: per-tile vmcnt(0) drain at
// __syncthreads capped avg in-flight at ~15KB/CU -> 3.9 TB/s delivery):
//   - hop_gemm: 5-deep LDS multi-buffer with counted vmcnt (T3+T4). Per tile
//     (K_TILE=64): A 4KB + B 8KB staged together via global_load_lds (B must
//     share the vmcnt stream: in-order retirement means any direct-global B
//     use would drain all older A prefetches). Per-wave 3 loads/tile; steady
//     state waits s_waitcnt vmcnt(12) -> 4 tiles (48KB/block) permanently in
//     flight, ~96KB/CU. Raw s_barrier (no vmcnt(0) drain).
//   - Waves now split N (wave w owns n-frag w for ALL of K): no cross-wave
//     reduction, acc is a single f32x4, direct coalesced stores.
//   - A swizzle involution kept: pre-swizzled global source (linear LDS dest)
//     + XOR'd ds_read, byte ^= ((row&7)<<4) within 128B blocks.
//   - prep / mlp unchanged.
// ---------------------------------------------------------------------------

#define N_NODES 8192
#define NDIM 64
#define K_TILE 64                   // floats of K per staged tile
#define NT (N_NODES / K_TILE)       // 128 tiles
#define ABYTES 4096                 // 16 rows x 64 floats x 4B
#define BBYTES 8192                 // 64 k x 64 n x 2B (bf16)
#define BUFB (ABYTES + BBYTES)      // 12288
#define NBUF 5                      // 61440 B LDS total (<= 64KB static)

typedef __attribute__((ext_vector_type(8))) short short8;   // 8 bf16 (4 VGPRs)
typedef __attribute__((ext_vector_type(4))) float f32x4;    // MFMA C/D

__device__ __forceinline__ unsigned int f2bf(float f) {
  // round-to-nearest-even fp32 -> bf16 bit pattern (data is finite)
  unsigned int u = __builtin_bit_cast(unsigned int, f);
  u += 0x7fffu + ((u >> 16) & 1u);
  return u >> 16;
}

__device__ __forceinline__ void async_copy16(void* lds, const void* g) {
  // 64 lanes x 16B: global[per-lane addr] -> LDS[uniform base + lane*16]
  __builtin_amdgcn_global_load_lds(
      (const __attribute__((address_space(1))) void*)g,
      (__attribute__((address_space(3))) void*)lds, 16, 0, 0);
}

// ---------------------------------------------------------------------------
// prep: Bp[((k>>3)*64 + n)*8 + (k&7)] = X[k][n]  (bf16), X = cat(x, wf)
// ---------------------------------------------------------------------------
__global__ void prep_kernel(const float* __restrict__ x,
                            const float* __restrict__ wf,
                            unsigned short* __restrict__ Bp) {
  int s = blockIdx.x * 256 + threadIdx.x;     // 0 .. 524287
  int khi = s >> 9;                           // k / 8
  int rem = s & 511;
  int n   = rem >> 3;
  int klo = rem & 7;
  int k   = (khi << 3) | klo;
  float v = (n < 48) ? x[k * 48 + n] : wf[k * 16 + (n - 48)];
  Bp[s] = (unsigned short)f2bf(v);
}

// ---------------------------------------------------------------------------
// hop_gemm: Y[h] = hop_h @ X   (M=8192, N=64, K=8192)
// grid = 1536 blocks (3 hops x 512 m-tiles of 16 rows), 256 threads (4 waves).
// Pipeline: NBUF=5 rotating 12KB buffers; iter t computes tile t from
// buf[t%5] and (after a read-done barrier) restages tile t+5 into the same
// buffer. Per-wave per-tile loads: 1x A (4 rows x 256B via one 1KB
// global_load_lds) + 2x B (1KB each). Residency: each wave waits
// vmcnt(3*(NBUF-1)=12) for its own tile-t loads, then s_barrier joins all
// waves. vmcnt never drains to 0 in the main loop.
// Wave w owns n-frag w: acc = one f32x4 over all 256 MFMAs.
// A frag: lane holds A[m=lane&15][ks*32 + (lane>>4)*8 + j], j=0..7.
// C/D: col = lane&15, row = (lane>>4)*4 + reg  (m89/m91-verified layout).
// ---------------------------------------------------------------------------
__global__ __launch_bounds__(256, 2) void hop_gemm(
    const float* __restrict__ hop1,
    const float* __restrict__ hop2,
    const float* __restrict__ hop3,
    const unsigned short* __restrict__ Bp,
    float* __restrict__ Y) {
  __shared__ __attribute__((aligned(16))) char ldsbuf[NBUF * BUFB];  // 60 KB

  int bid  = blockIdx.x;
  int h    = bid % 3;
  int mblk = bid / 3;
  const float* A = (h == 0) ? hop1 : (h == 1) ? hop2 : hop3;

  int tid  = threadIdx.x;
  int w    = tid >> 6;          // wave id = n-frag id
  int lane = tid & 63;
  int n0   = lane & 15;         // A row within tile / output col within frag
  int q    = lane >> 4;
  int swz  = (n0 & 7) << 4;     // read-side swizzle for this lane's frag row
  int wn0  = w * 16 + n0;       // output column

  // --- staging source pointers (per-lane, tile-0 based) ---
  // A: one instr/wave covers rows 4w..4w+3 (lane>>4 selects row), 256B each,
  //    column bytes (lane&15)*16 pre-XOR-swizzled by row (involution within
  //    each 128B half; LDS dest is linear lane*16).
  int arow = w * 4 + (lane >> 4);                    // 0..15
  const char* gAsrc = (const char*)A
      + ((size_t)(mblk * 16 + arow) << 15)           // global row * 32KB
      + (unsigned)((((lane & 15) << 4) ^ ((arow & 7) << 4)));
  // B: two instrs/wave, contiguous 1KB chunks of the packed Bp tile (8KB/tile
  //    = bytes [t*8192, +8192) of Bp, linear, no swizzle needed).
  const char* gBsrc = (const char*)Bp + ((w * 2) << 10) + (lane << 4);

  f32x4 acc = {0.f, 0.f, 0.f, 0.f};

#define STAGE(tt, bo_)                                                      \
  do {                                                                      \
    char* db = ldsbuf + (bo_);                                              \
    async_copy16(db + (w << 10), gAsrc + ((size_t)(tt) << 8));              \
    async_copy16(db + ABYTES + ((w * 2) << 10),                             \
                 gBsrc + ((size_t)(tt) << 13));                             \
    async_copy16(db + ABYTES + ((w * 2 + 1) << 10),                         \
                 gBsrc + ((size_t)(tt) << 13) + 1024);                      \
  } while (0)

  // One MFMA k-step: 32 k-values at within-tile k-offset ks*32.
#define KSTEP(bo_, ks)                                                       \
  do {                                                                      \
    const char* pA = ldsbuf + (bo_);                                        \
    int off0 = (n0 << 8) + ((((ks) << 7) + (q << 5)) ^ swz);                \
    float4 a0 = *(const float4*)(pA + off0);                                \
    float4 a1 = *(const float4*)(pA + (off0 ^ 16));                         \
    const short8* bp = (const short8*)(pA + ABYTES)                         \
                       + (((ks) * 4 + q) * 64 + wn0);                       \
    short8 b0 = bp[0];                                                      \
    union { short8 v; unsigned int u[4]; } af;                              \
    af.u[0] = (f2bf(a0.y) << 16) | f2bf(a0.x);                              \
    af.u[1] = (f2bf(a0.w) << 16) | f2bf(a0.z);                              \
    af.u[2] = (f2bf(a1.y) << 16) | f2bf(a1.x);                              \
    af.u[3] = (f2bf(a1.w) << 16) | f2bf(a1.z);                              \
    acc = __builtin_amdgcn_mfma_f32_16x16x32_bf16(af.v, b0, acc, 0, 0, 0);  \
  } while (0)

#define WAIT_BAR(n)                                                         \
  do {                                                                      \
    asm volatile("s_waitcnt vmcnt(" #n ")" ::: "memory");                   \
    __builtin_amdgcn_s_barrier();                                           \
    __builtin_amdgcn_sched_barrier(0);                                      \
  } while (0)

  // prologue: fill all 5 buffers (15 loads/wave outstanding)
  STAGE(0, 0 * BUFB);
  STAGE(1, 1 * BUFB);
  STAGE(2, 2 * BUFB);
  STAGE(3, 3 * BUFB);
  STAGE(4, 4 * BUFB);

  int bo = 0;
#pragma unroll 1
  for (int t = 0; t < NT - NBUF; ++t) {      // 123 iterations
    WAIT_BAR(12);                  // tile t resident (per-wave count + join)
    KSTEP(bo, 0);
    KSTEP(bo, 1);
    asm volatile("s_waitcnt lgkmcnt(0)" ::: "memory");
    __builtin_amdgcn_sched_barrier(0);
    __builtin_amdgcn_s_barrier();  // all waves done reading buf -> restage it
    STAGE(t + NBUF, bo);
    bo += BUFB;
    if (bo == NBUF * BUFB) bo = 0;
  }

  // epilogue: tiles NT-5..NT-1, outstanding shrinks 15->12->9->6->3->0
  WAIT_BAR(12); KSTEP(bo, 0); KSTEP(bo, 1);
  bo += BUFB; if (bo == NBUF * BUFB) bo = 0;
  WAIT_BAR(9);  KSTEP(bo, 0); KSTEP(bo, 1);
  bo += BUFB; if (bo == NBUF * BUFB) bo = 0;
  WAIT_BAR(6);  KSTEP(bo, 0); KSTEP(bo, 1);
  bo += BUFB; if (bo == NBUF * BUFB) bo = 0;
  WAIT_BAR(3);  KSTEP(bo, 0); KSTEP(bo, 1);
  bo += BUFB; if (bo == NBUF * BUFB) bo = 0;
  WAIT_BAR(0);  KSTEP(bo, 0); KSTEP(bo, 1);

#undef STAGE
#undef KSTEP
#undef WAIT_BAR

  // ---- store: wave w owns cols [w*16, w*16+16), no cross-wave reduction ----
  {
    float* Yo = Y + (size_t)h * (N_NODES * NDIM)
                  + (size_t)(mblk * 16 + q * 4) * NDIM + wn0;
    Yo[0 * NDIM] = acc.x;
    Yo[1 * NDIM] = acc.y;
    Yo[2 * NDIM] = acc.z;
    Yo[3 * NDIM] = acc.w;
  }
}

// ---------------------------------------------------------------------------
// mlp: out[row] = sum_k ( relu(Y_k[row] @ W1_k + b1_k) @ W2_k + b2_k )
// 512 blocks x 256 threads, 16 rows/block. fp32 VALU. Weights read straight
// from global (every block reads the same 256 KB -> L1/L2 resident).
// ---------------------------------------------------------------------------
#define YS_LD 68
#define HS_LD 132
__global__ __launch_bounds__(256) void mlp_kernel(
    const float* __restrict__ x, const float* __restrict__ wf,
    const float* __restrict__ Y,          // [3][8192][64]
    const float* __restrict__ W1, const float* __restrict__ b1,
    const float* __restrict__ W2, const float* __restrict__ b2,
    float* __restrict__ out) {
  __shared__ __attribute__((aligned(16))) float Ys[16 * YS_LD];   // 4.25 KB
  __shared__ __attribute__((aligned(16))) float Hs[16 * HS_LD];   // 8.25 KB
  __shared__ float b1s[128];
  __shared__ float b2s[64];

  int t = threadIdx.x;
  int rowBase = blockIdx.x * 16;

  int r  = t >> 4;           // 0..15: row (both layers)
  int c8 = (t & 15) * 8;     // layer-1 cols
  int c4 = (t & 15) * 4;     // layer-2 cols

  float oacc[4] = {0.f, 0.f, 0.f, 0.f};

  for (int k = 0; k < 4; ++k) {
    // ---- stage activations + biases ----
    for (int i = t; i < 16 * 64; i += 256) {
      int row = i >> 6;
      int n   = i & 63;
      float v;
      if (k == 0) {
        int grow = rowBase + row;
        v = (n < 48) ? x[grow * 48 + n] : wf[grow * 16 + (n - 48)];
      } else {
        v = Y[(size_t)(k - 1) * (N_NODES * 64) + (size_t)(rowBase + row) * 64 + n];
      }
      Ys[row * YS_LD + n] = v;
    }
    if (t < 128) b1s[t] = b1[k * 128 + t];
    else if (t < 192) b2s[t - 128] = b2[k * 64 + (t - 128)];
    __syncthreads();

    // ---- layer 1: H = relu(Ys @ W1 + b1), thread = 1 row x 8 cols ----
    const float* W1k = W1 + k * 8192;
    float f0 = 0.f, f1 = 0.f, f2 = 0.f, f3 = 0.f;
    float f4 = 0.f, f5 = 0.f, f6 = 0.f, f7 = 0.f;
#pragma unroll 4
    for (int kk = 0; kk < 64; ++kk) {
      float yv = Ys[r * YS_LD + kk];
      float4 w0 = *(const float4*)&W1k[kk * 128 + c8];
      float4 w1 = *(const float4*)&W1k[kk * 128 + c8 + 4];
      f0 = fmaf(yv, w0.x, f0); f1 = fmaf(yv, w0.y, f1);
      f2 = fmaf(yv, w0.z, f2); f3 = fmaf(yv, w0.w, f3);
      f4 = fmaf(yv, w1.x, f4); f5 = fmaf(yv, w1.y, f5);
      f6 = fmaf(yv, w1.z, f6); f7 = fmaf(yv, w1.w, f7);
    }
    {
      float4 ba = *(const float4*)&b1s[c8];
      float4 bb = *(const float4*)&b1s[c8 + 4];
      float4 h0, h1;
      h0.x = fmaxf(f0 + ba.x, 0.f); h0.y = fmaxf(f1 + ba.y, 0.f);
      h0.z = fmaxf(f2 + ba.z, 0.f); h0.w = fmaxf(f3 + ba.w, 0.f);
      h1.x = fmaxf(f4 + bb.x, 0.f); h1.y = fmaxf(f5 + bb.y, 0.f);
      h1.z = fmaxf(f6 + bb.z, 0.f); h1.w = fmaxf(f7 + bb.w, 0.f);
      *(float4*)&Hs[r * HS_LD + c8]     = h0;
      *(float4*)&Hs[r * HS_LD + c8 + 4] = h1;
    }
    __syncthreads();

    // ---- layer 2: out += Hs @ W2 + b2, thread = 1 row x 4 cols ----
    const float* W2k = W2 + k * 8192;
    float o0 = b2s[c4], o1 = b2s[c4 + 1], o2 = b2s[c4 + 2], o3 = b2s[c4 + 3];
#pragma unroll 4
    for (int kk = 0; kk < 128; ++kk) {
      float hv = Hs[r * HS_LD + kk];
      float4 wv = *(const float4*)&W2k[kk * 64 + c4];
      o0 = fmaf(hv, wv.x, o0); o1 = fmaf(hv, wv.y, o1);
      o2 = fmaf(hv, wv.z, o2); o3 = fmaf(hv, wv.w, o3);
    }
    oacc[0] += o0; oacc[1] += o1; oacc[2] += o2; oacc[3] += o3;
    __syncthreads();   // protect Ys/Hs before next branch restage
  }

  float4 v;
  v.x = oacc[0]; v.y = oacc[1]; v.z = oacc[2]; v.w = oacc[3];
  *(float4*)&out[(size_t)(rowBase + r) * 64 + c4] = v;
}

// ---------------------------------------------------------------------------
extern "C" void kernel_launch(void* const* d_in, const int* in_sizes, int n_in,
                              void* d_out, int out_size, void* d_ws, size_t ws_size,
                              hipStream_t stream) {
  const float* x    = (const float*)d_in[0];
  const float* wf   = (const float*)d_in[1];
  const float* hop1 = (const float*)d_in[2];
  const float* hop2 = (const float*)d_in[3];
  const float* hop3 = (const float*)d_in[4];
  const float* W1   = (const float*)d_in[5];
  const float* b1   = (const float*)d_in[6];
  const float* W2   = (const float*)d_in[7];
  const float* b2   = (const float*)d_in[8];
  float* out = (float*)d_out;

  // workspace layout: [0,1MB) packed bf16 X; [1MB, 1MB+6MB) Y[3][8192][64] f32
  unsigned short* Bp = (unsigned short*)d_ws;
  float* Y = (float*)((char*)d_ws + (1 << 20));

  prep_kernel<<<dim3(524288 / 256), dim3(256), 0, stream>>>(x, wf, Bp);
  hop_gemm<<<dim3(1536), dim3(256), 0, stream>>>(hop1, hop2, hop3, Bp, Y);
  mlp_kernel<<<dim3(512), dim3(256), 0, stream>>>(x, wf, Y, W1, b1, W2, b2, out);
}